// Round 9
// baseline (220.513 us; speedup 1.0000x reference)
//
#include <hip/hip_runtime.h>
#include <hip/hip_bf16.h>
#include <stdint.h>

#define EMBED 1024
#define HEADS 16
#define HDIM 64
#define SEQ 2048
#define BATCH 2
#define MTOT (BATCH*SEQ)   // 4096
#define KDIM EMBED         // 1024
#define HALFW 128

typedef __attribute__((ext_vector_type(8))) short short8;
typedef __attribute__((ext_vector_type(4))) float floatx4;

__device__ __forceinline__ ushort f2bf(float f){
  uint32_t x = __float_as_uint(f);
  x += 0x7fffu + ((x >> 16) & 1u);   // RNE
  return (ushort)(x >> 16);
}

__device__ __forceinline__ void gload16(const ushort* g, ushort* l){
  __builtin_amdgcn_global_load_lds(
      (__attribute__((address_space(1))) void*)(void*)g,
      (__attribute__((address_space(3))) void*)l, 16, 0, 0);
}

// ---------------- fused casts f32 -> bf16 (x, Wq, Wk, Wv, Wo) ----------------
__global__ void cast_all(const float* __restrict__ x,  ushort* __restrict__ xb,
                         const float* __restrict__ Wq, const float* __restrict__ Wk,
                         const float* __restrict__ Wv, ushort* __restrict__ wqkv,
                         const float* __restrict__ Wo, ushort* __restrict__ wo)
{
  int bid = blockIdx.x;
  const float* src; ushort* dst; int base;
  if (bid < 4096){ src = x;  dst = xb;   base = bid; }
  else {
    int seg = (bid - 4096) >> 10;            // 0..3
    int sb  = (bid - 4096) & 1023;
    base = sb;
    if      (seg == 0){ src = Wq; dst = wqkv;           }
    else if (seg == 1){ src = Wk; dst = wqkv + 1048576; }
    else if (seg == 2){ src = Wv; dst = wqkv + 2097152; }
    else              { src = Wo; dst = wo;             }
  }
  int i = (base * 256 + threadIdx.x) * 4;
  float4 v = *reinterpret_cast<const float4*>(src + i);
  ushort4 o;
  o.x = f2bf(v.x); o.y = f2bf(v.y); o.z = f2bf(v.z); o.w = f2bf(v.w);
  *reinterpret_cast<ushort4*>(dst + i) = o;
}

// ---------------- QKV GEMM: y = x @ W^T + b, write Q/K/V in [b,h,s,d] bf16 ----------------
// BM=128 x BN=256, BK=64, 4 waves (each wave: 128x64 output, 64 MFMA per barrier pair).
// Single-buffered 48 KB LDS -> 3 blocks/CU for cross-block latency overlap.
__global__ __launch_bounds__(256) void gemm_qkv(
    const ushort* __restrict__ A, const ushort* __restrict__ Bw,
    const float* __restrict__ biasq, const float* __restrict__ biask, const float* __restrict__ biasv,
    ushort* __restrict__ Qo, ushort* __restrict__ Ko, ushort* __restrict__ Vo)
{
  constexpr int BM = 128, BN = 256, BK = 64;
  __shared__ __attribute__((aligned(16))) ushort As[BM*BK];   // 16 KB
  __shared__ __attribute__((aligned(16))) ushort Bs[BN*BK];   // 32 KB
  const int tid  = threadIdx.x;
  const int lane = tid & 63;
  const int wn   = tid >> 6;          // wave 0..3 -> 64-col slice
  const int l15  = lane & 15;
  const int lhi  = lane >> 4;

  // XCD-aware bijective swizzle: 384 blocks, 48 per XCD; grid = 32 m-tiles x 12 n-tiles
  const int bid = blockIdx.x;
  const int swz = (bid & 7) * 48 + (bid >> 3);
  const int m0 = (swz & 31) * BM;
  const int n0 = (swz >> 5) * BN;

  floatx4 acc[8][4];
  #pragma unroll
  for (int i = 0; i < 8; ++i)
    #pragma unroll
    for (int j = 0; j < 4; ++j) acc[i][j] = (floatx4){0.f, 0.f, 0.f, 0.f};

  for (int kt = 0; kt < KDIM / BK; ++kt){
    const int kk = kt * BK;
    if (kt) __syncthreads();          // WAR: previous tile's reads complete
    #pragma unroll
    for (int i = 0; i < 4; ++i){      // A: 1024 chunks, 4/thread
      int c = tid + 256 * i;
      gload16(A + (size_t)(m0 + (c >> 3)) * KDIM + kk + (c & 7) * 8, &As[c * 8]);
    }
    #pragma unroll
    for (int i = 0; i < 8; ++i){      // B: 2048 chunks, 8/thread
      int c = tid + 256 * i;
      gload16(Bw + (size_t)(n0 + (c >> 3)) * KDIM + kk + (c & 7) * 8, &Bs[c * 8]);
    }
    __syncthreads();                  // drain stages (vmcnt+barrier)

    #pragma unroll
    for (int ksl = 0; ksl < 2; ++ksl){
      const int ko = ksl * 32 + lhi * 8;
      short8 af[8], bf[4];
      #pragma unroll
      for (int rt = 0; rt < 8; ++rt)
        af[rt] = *reinterpret_cast<const short8*>(&As[(rt*16 + l15) * BK + ko]);
      #pragma unroll
      for (int ct = 0; ct < 4; ++ct)
        bf[ct] = *reinterpret_cast<const short8*>(&Bs[(wn*64 + ct*16 + l15) * BK + ko]);
      #pragma unroll
      for (int rt = 0; rt < 8; ++rt)
        #pragma unroll
        for (int ct = 0; ct < 4; ++ct)
          acc[rt][ct] = __builtin_amdgcn_mfma_f32_16x16x32_bf16(af[rt], bf[ct], acc[rt][ct], 0, 0, 0);
    }
  }

  const int which = n0 >> 10;   // uniform per block: 0=Q 1=K 2=V (4 n-tiles per matrix)
  const float* bias = (which == 0) ? biasq : ((which == 1) ? biask : biasv);
  ushort* dst = (which == 0) ? Qo : ((which == 1) ? Ko : Vo);
  const int nb = n0 & 1023;
  #pragma unroll
  for (int rt = 0; rt < 8; ++rt)
    #pragma unroll
    for (int ct = 0; ct < 4; ++ct)
      #pragma unroll
      for (int r = 0; r < 4; ++r){
        int mg = m0 + rt*16 + lhi*4 + r;        // 0..4095
        int ng = nb + wn*64 + ct*16 + l15;       // 0..1023
        float v = acc[rt][ct][r] + bias[ng];
        int b = mg >> 11, s = mg & (SEQ - 1);
        int h = ng >> 6,  d = ng & 63;
        dst[(((size_t)(b*HEADS + h))*SEQ + s)*HDIM + d] = f2bf(v);
      }
}

// ---------------- V transpose: [b,h,s,d] -> [b,h,d,s] (LDS bounce, coalesced) ----------------
__global__ __launch_bounds__(256) void transposeV(const ushort* __restrict__ V,
                                                  ushort* __restrict__ Vt)
{
  __shared__ ushort t[64][72];
  const int tid = threadIdx.x;
  const int bh = blockIdx.y;
  const int s0 = blockIdx.x * 64;
  #pragma unroll
  for (int it = 0; it < 2; ++it){
    int idx = it * 256 + tid;            // 0..511
    int row = idx >> 3, off = (idx & 7) * 8;
    *reinterpret_cast<uint4*>(&t[row][off]) =
        *reinterpret_cast<const uint4*>(V + ((size_t)bh * SEQ + s0 + row) * HDIM + off);
  }
  __syncthreads();
  #pragma unroll
  for (int it = 0; it < 2; ++it){
    int idx = it * 256 + tid;
    int d = idx >> 3, soff = (idx & 7) * 8;
    short8 v;
    #pragma unroll
    for (int e = 0; e < 8; ++e) v[e] = (short)t[soff + e][d];
    *reinterpret_cast<short8*>(Vt + ((size_t)bh * HDIM + d) * SEQ + s0 + soff) = v;
  }
}

// ---------------- output GEMM: out = ao @ Wo^T + bo (fp32 out) ----------------
// BM=64 x BN=128 tiles -> 512 blocks (2 blocks/CU, 8 waves/CU).
__global__ __launch_bounds__(256) void gemm_out(
    const ushort* __restrict__ A, const ushort* __restrict__ Bw,
    const float* __restrict__ bias, float* __restrict__ Co)
{
  constexpr int BM = 64, BN = 128, BK = 32;
  __shared__ __attribute__((aligned(16))) ushort As[2][BM*BK];
  __shared__ __attribute__((aligned(16))) ushort Bs[2][BN*BK];
  const int tid  = threadIdx.x;
  const int lane = tid & 63;
  const int wc   = tid >> 6;     // wave 0..3 -> 32-col slice

  const int bid = blockIdx.x;
  const int swz = (bid & 7) * 64 + (bid >> 3);
  const int m0 = (swz & 63) * BM;
  const int n0 = (swz >> 6) * BN;

  const int rowA = tid >> 2, offA = (tid & 3) * 8;
  const ushort* Ap  = A  + (size_t)(m0 + rowA) * KDIM + offA;
  const ushort* Bp0 = Bw + (size_t)(n0 + rowA) * KDIM + offA;
  const ushort* Bp1 = Bw + (size_t)(n0 + 64 + rowA) * KDIM + offA;

  floatx4 acc[4][2];
  #pragma unroll
  for (int i = 0; i < 4; ++i)
    #pragma unroll
    for (int j = 0; j < 2; ++j) acc[i][j] = (floatx4){0.f, 0.f, 0.f, 0.f};

  const int rsel = lane & 15, ksel = (lane >> 4) * 8;

  gload16(Ap,  &As[0][tid * 8]);
  gload16(Bp0, &Bs[0][tid * 8]);
  gload16(Bp1, &Bs[0][(tid + 256) * 8]);
  __syncthreads();

  int cur = 0;
  for (int kk = 0; kk < KDIM; kk += BK){
    if (kk + BK < KDIM){
      gload16(Ap  + kk + BK, &As[cur ^ 1][tid * 8]);
      gload16(Bp0 + kk + BK, &Bs[cur ^ 1][tid * 8]);
      gload16(Bp1 + kk + BK, &Bs[cur ^ 1][(tid + 256) * 8]);
    }
    short8 af[4], bfr[2];
    #pragma unroll
    for (int m = 0; m < 4; ++m)
      af[m] = *reinterpret_cast<const short8*>(&As[cur][(m*16 + rsel) * BK + ksel]);
    #pragma unroll
    for (int n = 0; n < 2; ++n)
      bfr[n] = *reinterpret_cast<const short8*>(&Bs[cur][(wc*32 + n*16 + rsel) * BK + ksel]);
    #pragma unroll
    for (int m = 0; m < 4; ++m)
      #pragma unroll
      for (int n = 0; n < 2; ++n)
        acc[m][n] = __builtin_amdgcn_mfma_f32_16x16x32_bf16(af[m], bfr[n], acc[m][n], 0, 0, 0);
    __syncthreads();
    cur ^= 1;
  }

  #pragma unroll
  for (int m = 0; m < 4; ++m)
    #pragma unroll
    for (int n = 0; n < 2; ++n)
      #pragma unroll
      for (int r = 0; r < 4; ++r){
        int mg = m0 + m*16 + (lane >> 4)*4 + r;
        int ng = n0 + wc*32 + n*16 + (lane & 15);
        Co[(size_t)mg * EMBED + ng] = acc[m][n][r] + bias[ng];
      }
}

// ---------------- local attention: MFMA scores + softmax + full-row write + MFMA PV ----------------
__global__ __launch_bounds__(256) void attn_kernel(
    const ushort* __restrict__ Qb, const ushort* __restrict__ Kb, const ushort* __restrict__ Vt,
    float* __restrict__ attnp, ushort* __restrict__ ao)
{
  constexpr int TQ = 16;
  constexpr int SPAD = 292;   // f32 stride
  constexpr int PPAD = 296;   // ushort stride
  __shared__ __attribute__((aligned(16))) float  Ss[TQ][SPAD];
  __shared__ __attribute__((aligned(16))) ushort Pb[TQ][PPAD];
  __shared__ float rowinv[TQ];

  const int tid  = threadIdx.x;
  const int lane = tid & 63;
  const int w    = tid >> 6;      // wave 0..3
  const int l15  = lane & 15;
  const int lhi  = lane >> 4;     // 0..3
  const int qt = blockIdx.x;      // 0..127
  const int bh = blockIdx.y;      // 0..31
  const int q0 = qt * TQ;
  const int c0 = max(0, q0 - HALFW);
  const int c1 = min(SEQ, q0 + TQ + HALFW);   // c0,c1 multiples of 16
  const int nc = c1 - c0;                     // 144..272
  const int ntiles = nc >> 4;
  const int nks = (nc + 31) >> 5;             // 32-key slices for PV

  // ---- scores: S = Q @ K^T via mfma 16x16x32, straight from global ----
  const ushort* Qrow = Qb + ((size_t)bh * SEQ + q0 + l15) * HDIM + lhi * 8;
  const short8 aq0 = *reinterpret_cast<const short8*>(Qrow);
  const short8 aq1 = *reinterpret_cast<const short8*>(Qrow + 32);

  for (int t = w; t < ntiles; t += 4){
    const ushort* Krow = Kb + ((size_t)bh * SEQ + c0 + t*16 + l15) * HDIM + lhi * 8;
    short8 bk0 = *reinterpret_cast<const short8*>(Krow);
    short8 bk1 = *reinterpret_cast<const short8*>(Krow + 32);
    floatx4 acc = (floatx4){0.f, 0.f, 0.f, 0.f};
    acc = __builtin_amdgcn_mfma_f32_16x16x32_bf16(aq0, bk0, acc, 0, 0, 0);
    acc = __builtin_amdgcn_mfma_f32_16x16x32_bf16(aq1, bk1, acc, 0, 0, 0);
    const int c = c0 + t*16 + l15;
    #pragma unroll
    for (int r = 0; r < 4; ++r){
      int q = q0 + lhi*4 + r;
      float s = (c < q - HALFW || c > q + HALFW) ? -1e30f : acc[r] * 0.125f;
      Ss[lhi*4 + r][t*16 + l15] = s;
    }
  }
  __syncthreads();

  // ---- softmax over row r (16 threads per row) ----
  const int r  = tid >> 4;
  const int lc = tid & 15;
  float mx = -1e30f;
  for (int j = lc; j < nc; j += 16) mx = fmaxf(mx, Ss[r][j]);
  #pragma unroll
  for (int o = 1; o < 16; o <<= 1) mx = fmaxf(mx, __shfl_xor(mx, o, 64));
  float sum = 0.f;
  for (int j = lc; j < nc; j += 16){
    float p = __expf(Ss[r][j] - mx);
    Ss[r][j] = p;
    Pb[r][j] = f2bf(p);
    sum += p;
  }
  for (int j = nc + lc; j < nks * 32; j += 16) Pb[r][j] = 0;
  #pragma unroll
  for (int o = 1; o < 16; o <<= 1) sum += __shfl_xor(sum, o, 64);
  if (lc == 0) rowinv[r] = 1.f / sum;
  __syncthreads();

  // ---- full attn rows: zeros outside [c0,c1), p*inv inside ----
  const int jz0 = c0 >> 2, jz1 = c1 >> 2;
  const floatx4 zero4 = (floatx4){0.f, 0.f, 0.f, 0.f};
  for (int rr = 0; rr < TQ; ++rr){
    const float inv = rowinv[rr];
    floatx4* dst = reinterpret_cast<floatx4*>(attnp + ((size_t)bh * SEQ + (q0 + rr)) * SEQ);
    #pragma unroll
    for (int it = 0; it < SEQ / 4 / 256; ++it){
      int j4 = it * 256 + tid;
      floatx4 v = zero4;
      if (j4 >= jz0 && j4 < jz1){
        floatx4 p = *reinterpret_cast<const floatx4*>(&Ss[rr][j4 * 4 - c0]);
        v = (floatx4){p[0] * inv, p[1] * inv, p[2] * inv, p[3] * inv};
      }
      __builtin_nontemporal_store(v, &dst[j4]);
    }
  }

  // ---- PV via mfma: V from global (transposed layout) ----
  floatx4 oacc = (floatx4){0.f, 0.f, 0.f, 0.f};
  const ushort* Vrow = Vt + ((size_t)bh * HDIM + w*16 + l15) * SEQ + c0 + lhi * 8;
  for (int ks = 0; ks < nks; ++ks){
    short8 ap = *reinterpret_cast<const short8*>(&Pb[l15][ks*32 + lhi*8]);
    short8 bv = *reinterpret_cast<const short8*>(Vrow + ks*32);
    oacc = __builtin_amdgcn_mfma_f32_16x16x32_bf16(ap, bv, oacc, 0, 0, 0);
  }
  const int b = bh >> 4, h = bh & 15;
  #pragma unroll
  for (int rr = 0; rr < 4; ++rr){
    int q = q0 + lhi*4 + rr;
    float val = oacc[rr] * rowinv[lhi*4 + rr];
    ao[((size_t)(b * SEQ + q)) * EMBED + h * HDIM + w*16 + l15] = f2bf(val);
  }
}

extern "C" void kernel_launch(void* const* d_in, const int* in_sizes, int n_in,
                              void* d_out, int out_size, void* d_ws, size_t ws_size,
                              hipStream_t stream)
{
  const float* x  = (const float*)d_in[0];
  const float* Wq = (const float*)d_in[1];
  const float* bq = (const float*)d_in[2];
  const float* Wk = (const float*)d_in[3];
  const float* bk = (const float*)d_in[4];
  const float* Wv = (const float*)d_in[5];
  const float* bv = (const float*)d_in[6];
  const float* Wo = (const float*)d_in[7];
  const float* bo = (const float*)d_in[8];

  char* ws = (char*)d_ws;
  ushort* xb   = (ushort*)(ws);                 // x bf16 [4096][1024]   (reused as Vt later)
  ushort* wqkv = (ushort*)(ws + 8388608);       // Wq|Wk|Wv bf16
  ushort* wo   = (ushort*)(ws + 14680064);      // Wo bf16
  ushort* Qb   = (ushort*)(ws + 16777216);      // Q bf16 [b,h,s,d]
  ushort* Kb   = (ushort*)(ws + 25165824);      // K bf16 [b,h,s,d]
  ushort* Vb   = (ushort*)(ws + 33554432);      // V bf16 [b,h,s,d]
  ushort* ao   = (ushort*)(ws + 41943040);      // attn out bf16 [b,s,e]
  ushort* Vt   = (ushort*)(ws);                 // V^T bf16 [b,h,d,s] — aliases xb (dead after gemm_qkv)

  float* outp  = (float*)d_out;                           // [2,2048,1024]
  float* attnp = outp + (size_t)MTOT * EMBED;             // [2,16,2048,2048]

  cast_all<<<8192, 256, 0, stream>>>(x, xb, Wq, Wk, Wv, wqkv, Wo, wo);
  gemm_qkv<<<384, 256, 0, stream>>>(xb, wqkv, bq, bk, bv, Qb, Kb, Vb);
  transposeV<<<dim3(32, 32), 256, 0, stream>>>(Vb, Vt);
  attn_kernel<<<dim3(128, 32), 256, 0, stream>>>(Qb, Kb, Vt, attnp, ao);
  gemm_out<<<512, 256, 0, stream>>>(ao, wo, bo, outp);
}

// Round 10
// 181.698 us; speedup vs baseline: 1.2136x; 1.2136x over previous
//
#include <hip/hip_runtime.h>
#include <hip/hip_bf16.h>
#include <stdint.h>

#define EMBED 1024
#define HEADS 16
#define HDIM 64
#define SEQ 2048
#define BATCH 2
#define MTOT (BATCH*SEQ)   // 4096
#define KDIM EMBED         // 1024
#define HALFW 128

typedef __attribute__((ext_vector_type(8))) short short8;
typedef __attribute__((ext_vector_type(4))) float floatx4;

__device__ __forceinline__ ushort f2bf(float f){
  uint32_t x = __float_as_uint(f);
  x += 0x7fffu + ((x >> 16) & 1u);   // RNE
  return (ushort)(x >> 16);
}

__device__ __forceinline__ void gload16(const ushort* g, ushort* l){
  __builtin_amdgcn_global_load_lds(
      (__attribute__((address_space(1))) void*)(void*)g,
      (__attribute__((address_space(3))) void*)l, 16, 0, 0);
}

// ---------------- fused casts f32 -> bf16 (x, Wq, Wk, Wv, Wo) ----------------
__global__ void cast_all(const float* __restrict__ x,  ushort* __restrict__ xb,
                         const float* __restrict__ Wq, const float* __restrict__ Wk,
                         const float* __restrict__ Wv, ushort* __restrict__ wqkv,
                         const float* __restrict__ Wo, ushort* __restrict__ wo)
{
  int bid = blockIdx.x;
  const float* src; ushort* dst; int base;
  if (bid < 4096){ src = x;  dst = xb;   base = bid; }
  else {
    int seg = (bid - 4096) >> 10;            // 0..3
    int sb  = (bid - 4096) & 1023;
    base = sb;
    if      (seg == 0){ src = Wq; dst = wqkv;           }
    else if (seg == 1){ src = Wk; dst = wqkv + 1048576; }
    else if (seg == 2){ src = Wv; dst = wqkv + 2097152; }
    else              { src = Wo; dst = wo;             }
  }
  int i = (base * 256 + threadIdx.x) * 4;
  float4 v = *reinterpret_cast<const float4*>(src + i);
  ushort4 o;
  o.x = f2bf(v.x); o.y = f2bf(v.y); o.z = f2bf(v.z); o.w = f2bf(v.w);
  *reinterpret_cast<ushort4*>(dst + i) = o;
}

// ---------------- QKV GEMM: y = x @ W^T + b, write Q/K/V in [b,h,s,d] bf16 ----------------
// 2-phase double-buffered staging. XCD swizzle: m pinned per XCD (A-panel L2-hot), n fast.
__global__ __launch_bounds__(256) void gemm_qkv(
    const ushort* __restrict__ A, const ushort* __restrict__ Bw,
    const float* __restrict__ biasq, const float* __restrict__ biask, const float* __restrict__ biasv,
    ushort* __restrict__ Qo, ushort* __restrict__ Ko, ushort* __restrict__ Vo)
{
  constexpr int BM = 128, BN = 128, BK = 32;
  __shared__ __attribute__((aligned(16))) ushort As[2][BM*BK];
  __shared__ __attribute__((aligned(16))) ushort Bs[2][BN*BK];
  const int tid  = threadIdx.x;
  const int lane = tid & 63;
  const int wid  = tid >> 6;
  const int wr = wid >> 1, wc = wid & 1;

  // 768 blocks = 32 m-tiles x 24 n-tiles; 96 per XCD = 4 m x 24 n (n cycles fast)
  const int bid = blockIdx.x;
  const int xcd = bid & 7, i = bid >> 3;       // i in 0..95
  const int m0 = (xcd * 4 + i / 24) * BM;
  const int n0 = (i % 24) * BN;

  const int cc0 = tid, cc1 = tid + 256;
  const int row0 = cc0 >> 2, off0 = (cc0 & 3) * 8;
  const int row1 = cc1 >> 2, off1 = (cc1 & 3) * 8;
  const ushort* A0 = A  + (size_t)(m0 + row0) * KDIM + off0;
  const ushort* A1 = A  + (size_t)(m0 + row1) * KDIM + off1;
  const ushort* B0 = Bw + (size_t)(n0 + row0) * KDIM + off0;
  const ushort* B1 = Bw + (size_t)(n0 + row1) * KDIM + off1;

  floatx4 acc[4][4];
  #pragma unroll
  for (int ii = 0; ii < 4; ++ii)
    #pragma unroll
    for (int j = 0; j < 4; ++j) acc[ii][j] = (floatx4){0.f, 0.f, 0.f, 0.f};

  const int rsel = lane & 15, ksel = (lane >> 4) * 8;

  gload16(A0, &As[0][cc0 * 8]);
  gload16(B0, &Bs[0][cc0 * 8]);
  gload16(A1, &As[0][cc1 * 8]);
  gload16(B1, &Bs[0][cc1 * 8]);
  __syncthreads();

  int cur = 0;
  for (int kk = 0; kk < KDIM; kk += BK){
    if (kk + BK < KDIM){
      gload16(A0 + kk + BK, &As[cur ^ 1][cc0 * 8]);
      gload16(B0 + kk + BK, &Bs[cur ^ 1][cc0 * 8]);
      gload16(A1 + kk + BK, &As[cur ^ 1][cc1 * 8]);
      gload16(B1 + kk + BK, &Bs[cur ^ 1][cc1 * 8]);
    }
    short8 af[4], bfr[4];
    #pragma unroll
    for (int m = 0; m < 4; ++m)
      af[m] = *reinterpret_cast<const short8*>(&As[cur][(wr*64 + m*16 + rsel) * BK + ksel]);
    #pragma unroll
    for (int n = 0; n < 4; ++n)
      bfr[n] = *reinterpret_cast<const short8*>(&Bs[cur][(wc*64 + n*16 + rsel) * BK + ksel]);
    #pragma unroll
    for (int m = 0; m < 4; ++m)
      #pragma unroll
      for (int n = 0; n < 4; ++n)
        acc[m][n] = __builtin_amdgcn_mfma_f32_16x16x32_bf16(af[m], bfr[n], acc[m][n], 0, 0, 0);
    __syncthreads();
    cur ^= 1;
  }

  const int which = n0 >> 10;   // uniform per block: 0=Q 1=K 2=V
  const float* bias = (which == 0) ? biasq : ((which == 1) ? biask : biasv);
  ushort* dst = (which == 0) ? Qo : ((which == 1) ? Ko : Vo);
  const int nb = n0 & 1023;
  #pragma unroll
  for (int m = 0; m < 4; ++m)
    #pragma unroll
    for (int n = 0; n < 4; ++n)
      #pragma unroll
      for (int r = 0; r < 4; ++r){
        int mg = m0 + wr*64 + m*16 + (lane >> 4)*4 + r;   // 0..4095
        int ng = nb + wc*64 + n*16 + (lane & 15);          // 0..1023
        float v = acc[m][n][r] + bias[ng];
        int b = mg >> 11, s = mg & (SEQ - 1);
        int h = ng >> 6,  d = ng & 63;
        dst[(((size_t)(b*HEADS + h))*SEQ + s)*HDIM + d] = f2bf(v);
      }
}

// ---------------- V transpose: [b,h,s,d] -> [b,h,d,s] (LDS bounce, coalesced) ----------------
__global__ __launch_bounds__(256) void transposeV(const ushort* __restrict__ V,
                                                  ushort* __restrict__ Vt)
{
  __shared__ ushort t[64][72];
  const int tid = threadIdx.x;
  const int bh = blockIdx.y;
  const int s0 = blockIdx.x * 64;
  #pragma unroll
  for (int it = 0; it < 2; ++it){
    int idx = it * 256 + tid;            // 0..511
    int row = idx >> 3, off = (idx & 7) * 8;
    *reinterpret_cast<uint4*>(&t[row][off]) =
        *reinterpret_cast<const uint4*>(V + ((size_t)bh * SEQ + s0 + row) * HDIM + off);
  }
  __syncthreads();
  #pragma unroll
  for (int it = 0; it < 2; ++it){
    int idx = it * 256 + tid;
    int d = idx >> 3, soff = (idx & 7) * 8;
    short8 v;
    #pragma unroll
    for (int e = 0; e < 8; ++e) v[e] = (short)t[soff + e][d];
    *reinterpret_cast<short8*>(Vt + ((size_t)bh * HDIM + d) * SEQ + s0 + soff) = v;
  }
}

// ---------------- output GEMM: out = ao @ Wo^T + bo (fp32 out) ----------------
// 2-phase double-buffered; 256 blocks = 32 m x 8 n; m pinned per XCD, n fast.
__global__ __launch_bounds__(256) void gemm_out(
    const ushort* __restrict__ A, const ushort* __restrict__ Bw,
    const float* __restrict__ bias, float* __restrict__ Co)
{
  constexpr int BM = 128, BN = 128, BK = 32;
  __shared__ __attribute__((aligned(16))) ushort As[2][BM*BK];
  __shared__ __attribute__((aligned(16))) ushort Bs[2][BN*BK];
  const int tid  = threadIdx.x;
  const int lane = tid & 63;
  const int wid  = tid >> 6;
  const int wr = wid >> 1, wc = wid & 1;

  const int bid = blockIdx.x;
  const int xcd = bid & 7, i = bid >> 3;       // i in 0..31
  const int m0 = (xcd * 4 + (i >> 3)) * BM;
  const int n0 = (i & 7) * BN;

  const int cc0 = tid, cc1 = tid + 256;
  const int row0 = cc0 >> 2, off0 = (cc0 & 3) * 8;
  const int row1 = cc1 >> 2, off1 = (cc1 & 3) * 8;
  const ushort* A0 = A  + (size_t)(m0 + row0) * KDIM + off0;
  const ushort* A1 = A  + (size_t)(m0 + row1) * KDIM + off1;
  const ushort* B0 = Bw + (size_t)(n0 + row0) * KDIM + off0;
  const ushort* B1 = Bw + (size_t)(n0 + row1) * KDIM + off1;

  floatx4 acc[4][4];
  #pragma unroll
  for (int ii = 0; ii < 4; ++ii)
    #pragma unroll
    for (int j = 0; j < 4; ++j) acc[ii][j] = (floatx4){0.f, 0.f, 0.f, 0.f};

  const int rsel = lane & 15, ksel = (lane >> 4) * 8;

  gload16(A0, &As[0][cc0 * 8]);
  gload16(B0, &Bs[0][cc0 * 8]);
  gload16(A1, &As[0][cc1 * 8]);
  gload16(B1, &Bs[0][cc1 * 8]);
  __syncthreads();

  int cur = 0;
  for (int kk = 0; kk < KDIM; kk += BK){
    if (kk + BK < KDIM){
      gload16(A0 + kk + BK, &As[cur ^ 1][cc0 * 8]);
      gload16(B0 + kk + BK, &Bs[cur ^ 1][cc0 * 8]);
      gload16(A1 + kk + BK, &As[cur ^ 1][cc1 * 8]);
      gload16(B1 + kk + BK, &Bs[cur ^ 1][cc1 * 8]);
    }
    short8 af[4], bfr[4];
    #pragma unroll
    for (int m = 0; m < 4; ++m)
      af[m] = *reinterpret_cast<const short8*>(&As[cur][(wr*64 + m*16 + rsel) * BK + ksel]);
    #pragma unroll
    for (int n = 0; n < 4; ++n)
      bfr[n] = *reinterpret_cast<const short8*>(&Bs[cur][(wc*64 + n*16 + rsel) * BK + ksel]);
    #pragma unroll
    for (int m = 0; m < 4; ++m)
      #pragma unroll
      for (int n = 0; n < 4; ++n)
        acc[m][n] = __builtin_amdgcn_mfma_f32_16x16x32_bf16(af[m], bfr[n], acc[m][n], 0, 0, 0);
    __syncthreads();
    cur ^= 1;
  }

  #pragma unroll
  for (int m = 0; m < 4; ++m)
    #pragma unroll
    for (int n = 0; n < 4; ++n)
      #pragma unroll
      for (int r = 0; r < 4; ++r){
        int mg = m0 + wr*64 + m*16 + (lane >> 4)*4 + r;
        int ng = n0 + wc*64 + n*16 + (lane & 15);
        Co[(size_t)mg * EMBED + ng] = acc[m][n][r] + bias[ng];
      }
}

// ---------------- local attention: MFMA scores + softmax + full-row write + MFMA PV ----------------
__global__ __launch_bounds__(256) void attn_kernel(
    const ushort* __restrict__ Qb, const ushort* __restrict__ Kb, const ushort* __restrict__ Vt,
    float* __restrict__ attnp, ushort* __restrict__ ao)
{
  constexpr int TQ = 16;
  constexpr int SPAD = 292;   // f32 stride
  constexpr int PPAD = 296;   // ushort stride
  __shared__ __attribute__((aligned(16))) float  Ss[TQ][SPAD];
  __shared__ __attribute__((aligned(16))) ushort Pb[TQ][PPAD];
  __shared__ float rowinv[TQ];

  const int tid  = threadIdx.x;
  const int lane = tid & 63;
  const int w    = tid >> 6;      // wave 0..3
  const int l15  = lane & 15;
  const int lhi  = lane >> 4;     // 0..3
  const int qt = blockIdx.x;      // 0..127
  const int bh = blockIdx.y;      // 0..31
  const int q0 = qt * TQ;
  const int c0 = max(0, q0 - HALFW);
  const int c1 = min(SEQ, q0 + TQ + HALFW);   // c0,c1 multiples of 16
  const int nc = c1 - c0;                     // 144..272
  const int ntiles = nc >> 4;
  const int nks = (nc + 31) >> 5;             // 32-key slices for PV

  // ---- scores: S = Q @ K^T via mfma 16x16x32, straight from global ----
  const ushort* Qrow = Qb + ((size_t)bh * SEQ + q0 + l15) * HDIM + lhi * 8;
  const short8 aq0 = *reinterpret_cast<const short8*>(Qrow);
  const short8 aq1 = *reinterpret_cast<const short8*>(Qrow + 32);

  for (int t = w; t < ntiles; t += 4){
    const ushort* Krow = Kb + ((size_t)bh * SEQ + c0 + t*16 + l15) * HDIM + lhi * 8;
    short8 bk0 = *reinterpret_cast<const short8*>(Krow);
    short8 bk1 = *reinterpret_cast<const short8*>(Krow + 32);
    floatx4 acc = (floatx4){0.f, 0.f, 0.f, 0.f};
    acc = __builtin_amdgcn_mfma_f32_16x16x32_bf16(aq0, bk0, acc, 0, 0, 0);
    acc = __builtin_amdgcn_mfma_f32_16x16x32_bf16(aq1, bk1, acc, 0, 0, 0);
    const int c = c0 + t*16 + l15;
    #pragma unroll
    for (int r = 0; r < 4; ++r){
      int q = q0 + lhi*4 + r;
      float s = (c < q - HALFW || c > q + HALFW) ? -1e30f : acc[r] * 0.125f;
      Ss[lhi*4 + r][t*16 + l15] = s;
    }
  }
  __syncthreads();

  // ---- softmax over row r (16 threads per row) ----
  const int r  = tid >> 4;
  const int lc = tid & 15;
  float mx = -1e30f;
  for (int j = lc; j < nc; j += 16) mx = fmaxf(mx, Ss[r][j]);
  #pragma unroll
  for (int o = 1; o < 16; o <<= 1) mx = fmaxf(mx, __shfl_xor(mx, o, 64));
  float sum = 0.f;
  for (int j = lc; j < nc; j += 16){
    float p = __expf(Ss[r][j] - mx);
    Ss[r][j] = p;
    Pb[r][j] = f2bf(p);
    sum += p;
  }
  for (int j = nc + lc; j < nks * 32; j += 16) Pb[r][j] = 0;
  #pragma unroll
  for (int o = 1; o < 16; o <<= 1) sum += __shfl_xor(sum, o, 64);
  if (lc == 0) rowinv[r] = 1.f / sum;
  __syncthreads();

  // ---- full attn rows: zeros outside [c0,c1), p*inv inside ----
  const int jz0 = c0 >> 2, jz1 = c1 >> 2;
  const floatx4 zero4 = (floatx4){0.f, 0.f, 0.f, 0.f};
  for (int rr = 0; rr < TQ; ++rr){
    const float inv = rowinv[rr];
    floatx4* dst = reinterpret_cast<floatx4*>(attnp + ((size_t)bh * SEQ + (q0 + rr)) * SEQ);
    #pragma unroll
    for (int it = 0; it < SEQ / 4 / 256; ++it){
      int j4 = it * 256 + tid;
      floatx4 v = zero4;
      if (j4 >= jz0 && j4 < jz1){
        floatx4 p = *reinterpret_cast<const floatx4*>(&Ss[rr][j4 * 4 - c0]);
        v = (floatx4){p[0] * inv, p[1] * inv, p[2] * inv, p[3] * inv};
      }
      __builtin_nontemporal_store(v, &dst[j4]);
    }
  }

  // ---- PV via mfma: V from global (transposed layout) ----
  floatx4 oacc = (floatx4){0.f, 0.f, 0.f, 0.f};
  const ushort* Vrow = Vt + ((size_t)bh * HDIM + w*16 + l15) * SEQ + c0 + lhi * 8;
  for (int ks = 0; ks < nks; ++ks){
    short8 ap = *reinterpret_cast<const short8*>(&Pb[l15][ks*32 + lhi*8]);
    short8 bv = *reinterpret_cast<const short8*>(Vrow + ks*32);
    oacc = __builtin_amdgcn_mfma_f32_16x16x32_bf16(ap, bv, oacc, 0, 0, 0);
  }
  const int b = bh >> 4, h = bh & 15;
  #pragma unroll
  for (int rr = 0; rr < 4; ++rr){
    int q = q0 + lhi*4 + rr;
    float val = oacc[rr] * rowinv[lhi*4 + rr];
    ao[((size_t)(b * SEQ + q)) * EMBED + h * HDIM + w*16 + l15] = f2bf(val);
  }
}

extern "C" void kernel_launch(void* const* d_in, const int* in_sizes, int n_in,
                              void* d_out, int out_size, void* d_ws, size_t ws_size,
                              hipStream_t stream)
{
  const float* x  = (const float*)d_in[0];
  const float* Wq = (const float*)d_in[1];
  const float* bq = (const float*)d_in[2];
  const float* Wk = (const float*)d_in[3];
  const float* bk = (const float*)d_in[4];
  const float* Wv = (const float*)d_in[5];
  const float* bv = (const float*)d_in[6];
  const float* Wo = (const float*)d_in[7];
  const float* bo = (const float*)d_in[8];

  char* ws = (char*)d_ws;
  ushort* xb   = (ushort*)(ws);                 // x bf16 [4096][1024]   (reused as Vt later)
  ushort* wqkv = (ushort*)(ws + 8388608);       // Wq|Wk|Wv bf16
  ushort* wo   = (ushort*)(ws + 14680064);      // Wo bf16
  ushort* Qb   = (ushort*)(ws + 16777216);      // Q bf16 [b,h,s,d]
  ushort* Kb   = (ushort*)(ws + 25165824);      // K bf16 [b,h,s,d]
  ushort* Vb   = (ushort*)(ws + 33554432);      // V bf16 [b,h,s,d]
  ushort* ao   = (ushort*)(ws + 41943040);      // attn out bf16 [b,s,e]
  ushort* Vt   = (ushort*)(ws);                 // V^T bf16 [b,h,d,s] — aliases xb (dead after gemm_qkv)

  float* outp  = (float*)d_out;                           // [2,2048,1024]
  float* attnp = outp + (size_t)MTOT * EMBED;             // [2,16,2048,2048]

  cast_all<<<8192, 256, 0, stream>>>(x, xb, Wq, Wk, Wv, wqkv, Wo, wo);
  gemm_qkv<<<768, 256, 0, stream>>>(xb, wqkv, bq, bk, bv, Qb, Kb, Vb);
  transposeV<<<dim3(32, 32), 256, 0, stream>>>(Vb, Vt);
  attn_kernel<<<dim3(128, 32), 256, 0, stream>>>(Qb, Kb, Vt, attnp, ao);
  gemm_out<<<256, 256, 0, stream>>>(ao, wo, bo, outp);
}

// Round 11
// 181.552 us; speedup vs baseline: 1.2146x; 1.0008x over previous
//
#include <hip/hip_runtime.h>
#include <hip/hip_bf16.h>
#include <stdint.h>

#define EMBED 1024
#define HEADS 16
#define HDIM 64
#define SEQ 2048
#define BATCH 2
#define MTOT (BATCH*SEQ)   // 4096
#define KDIM EMBED         // 1024
#define HALFW 128

typedef __attribute__((ext_vector_type(8))) short short8;
typedef __attribute__((ext_vector_type(4))) float floatx4;
typedef __attribute__((ext_vector_type(16))) float floatx16;

__device__ __forceinline__ ushort f2bf(float f){
  uint32_t x = __float_as_uint(f);
  x += 0x7fffu + ((x >> 16) & 1u);   // RNE
  return (ushort)(x >> 16);
}

__device__ __forceinline__ void gload16(const ushort* g, ushort* l){
  __builtin_amdgcn_global_load_lds(
      (__attribute__((address_space(1))) void*)(void*)g,
      (__attribute__((address_space(3))) void*)l, 16, 0, 0);
}

// ---------------- fused casts f32 -> bf16 (x, Wq, Wk, Wv, Wo) ----------------
__global__ void cast_all(const float* __restrict__ x,  ushort* __restrict__ xb,
                         const float* __restrict__ Wq, const float* __restrict__ Wk,
                         const float* __restrict__ Wv, ushort* __restrict__ wqkv,
                         const float* __restrict__ Wo, ushort* __restrict__ wo)
{
  int bid = blockIdx.x;
  const float* src; ushort* dst; int base;
  if (bid < 4096){ src = x;  dst = xb;   base = bid; }
  else {
    int seg = (bid - 4096) >> 10;            // 0..3
    int sb  = (bid - 4096) & 1023;
    base = sb;
    if      (seg == 0){ src = Wq; dst = wqkv;           }
    else if (seg == 1){ src = Wk; dst = wqkv + 1048576; }
    else if (seg == 2){ src = Wv; dst = wqkv + 2097152; }
    else              { src = Wo; dst = wo;             }
  }
  int i = (base * 256 + threadIdx.x) * 4;
  float4 v = *reinterpret_cast<const float4*>(src + i);
  ushort4 o;
  o.x = f2bf(v.x); o.y = f2bf(v.y); o.z = f2bf(v.z); o.w = f2bf(v.w);
  *reinterpret_cast<ushort4*>(dst + i) = o;
}

// ---------------- QKV GEMM: y = x @ W^T + b, write Q/K/V in [b,h,s,d] bf16 ----------------
// mfma 32x32x16: 2x2 waves, each 64x64 out via 2x2 frags of 32x32.
// T2 XOR-swizzle (k8-slot ^ row-bits 2-3): linear LDS dest for gload_lds,
// inverse-swizzled GLOBAL source, same swizzle on ds_read (rule #21).
__global__ __launch_bounds__(256) void gemm_qkv(
    const ushort* __restrict__ A, const ushort* __restrict__ Bw,
    const float* __restrict__ biasq, const float* __restrict__ biask, const float* __restrict__ biasv,
    ushort* __restrict__ Qo, ushort* __restrict__ Ko, ushort* __restrict__ Vo)
{
  constexpr int BM = 128, BN = 128, BK = 32;
  __shared__ __attribute__((aligned(16))) ushort As[2][BM*BK];
  __shared__ __attribute__((aligned(16))) ushort Bs[2][BN*BK];
  const int tid  = threadIdx.x;
  const int lane = tid & 63;
  const int wid  = tid >> 6;
  const int wr = wid >> 1, wc = wid & 1;
  const int l31 = lane & 31;
  const int lh  = lane >> 5;          // 0..1

  // 768 blocks = 32 m x 24 n; m pinned per XCD, n fast
  const int bid = blockIdx.x;
  const int xcd = bid & 7, ib = bid >> 3;      // ib in 0..95
  const int m0 = (xcd * 4 + ib / 24) * BM;
  const int n0 = (ib % 24) * BN;

  // staging: chunk c (0..511) -> lds row=c>>2, slot=c&3; source k8 = slot ^ ((row>>2)&3)
  const int c0 = tid,          r0 = c0 >> 2, k80 = (c0 & 3) ^ ((c0 >> 4) & 3);
  const int c1 = tid + 256,    r1 = c1 >> 2, k81 = (c1 & 3) ^ ((c1 >> 4) & 3);
  const ushort* A0 = A  + (size_t)(m0 + r0) * KDIM + k80 * 8;
  const ushort* A1 = A  + (size_t)(m0 + r1) * KDIM + k81 * 8;
  const ushort* B0 = Bw + (size_t)(n0 + r0) * KDIM + k80 * 8;
  const ushort* B1 = Bw + (size_t)(n0 + r1) * KDIM + k81 * 8;

  floatx16 acc[2][2];
  #pragma unroll
  for (int i = 0; i < 2; ++i)
    #pragma unroll
    for (int j = 0; j < 2; ++j)
      #pragma unroll
      for (int e = 0; e < 16; ++e) acc[i][j][e] = 0.f;

  // fragment read offsets (ushort index): row*32 + (slot ^ ((row>>2)&3))*8
  int aoff[2][2], boff[2][2];   // [rt|ct][ksl]
  #pragma unroll
  for (int rt = 0; rt < 2; ++rt){
    int rowa = wr*64 + rt*32 + l31;
    int rowb = wc*64 + rt*32 + l31;
    int g = (l31 >> 2) & 3;
    #pragma unroll
    for (int ksl = 0; ksl < 2; ++ksl){
      aoff[rt][ksl] = rowa*32 + ((ksl*2 + lh) ^ g) * 8;
      boff[rt][ksl] = rowb*32 + ((ksl*2 + lh) ^ g) * 8;
    }
  }

  gload16(A0, &As[0][c0 * 8]);
  gload16(B0, &Bs[0][c0 * 8]);
  gload16(A1, &As[0][c1 * 8]);
  gload16(B1, &Bs[0][c1 * 8]);
  __syncthreads();

  int cur = 0;
  for (int kk = 0; kk < KDIM; kk += BK){
    if (kk + BK < KDIM){
      gload16(A0 + kk + BK, &As[cur ^ 1][c0 * 8]);
      gload16(B0 + kk + BK, &Bs[cur ^ 1][c0 * 8]);
      gload16(A1 + kk + BK, &As[cur ^ 1][c1 * 8]);
      gload16(B1 + kk + BK, &Bs[cur ^ 1][c1 * 8]);
    }
    #pragma unroll
    for (int ksl = 0; ksl < 2; ++ksl){
      short8 af[2], bf[2];
      #pragma unroll
      for (int rt = 0; rt < 2; ++rt)
        af[rt] = *reinterpret_cast<const short8*>(&As[cur][aoff[rt][ksl]]);
      #pragma unroll
      for (int ct = 0; ct < 2; ++ct)
        bf[ct] = *reinterpret_cast<const short8*>(&Bs[cur][boff[ct][ksl]]);
      #pragma unroll
      for (int rt = 0; rt < 2; ++rt)
        #pragma unroll
        for (int ct = 0; ct < 2; ++ct)
          acc[rt][ct] = __builtin_amdgcn_mfma_f32_32x32x16_bf16(af[rt], bf[ct], acc[rt][ct], 0, 0, 0);
    }
    __syncthreads();
    cur ^= 1;
  }

  const int which = n0 >> 10;   // uniform per block: 0=Q 1=K 2=V
  const float* bias = (which == 0) ? biasq : ((which == 1) ? biask : biasv);
  ushort* dst = (which == 0) ? Qo : ((which == 1) ? Ko : Vo);
  const int nb = n0 & 1023;
  // C layout 32x32: col = lane&31, row = (reg&3) + 8*(reg>>2) + 4*(lane>>5)
  #pragma unroll
  for (int rt = 0; rt < 2; ++rt)
    #pragma unroll
    for (int ct = 0; ct < 2; ++ct)
      #pragma unroll
      for (int reg = 0; reg < 16; ++reg){
        int row = (reg & 3) + 8 * (reg >> 2) + 4 * lh;
        int mg = m0 + wr*64 + rt*32 + row;        // 0..4095
        int ng = nb + wc*64 + ct*32 + l31;         // 0..1023
        float v = acc[rt][ct][reg] + bias[ng];
        int b = mg >> 11, s = mg & (SEQ - 1);
        int h = ng >> 6,  d = ng & 63;
        dst[(((size_t)(b*HEADS + h))*SEQ + s)*HDIM + d] = f2bf(v);
      }
}

// ---------------- V transpose: [b,h,s,d] -> [b,h,d,s] (LDS bounce, coalesced) ----------------
__global__ __launch_bounds__(256) void transposeV(const ushort* __restrict__ V,
                                                  ushort* __restrict__ Vt)
{
  __shared__ ushort t[64][72];
  const int tid = threadIdx.x;
  const int bh = blockIdx.y;
  const int s0 = blockIdx.x * 64;
  #pragma unroll
  for (int it = 0; it < 2; ++it){
    int idx = it * 256 + tid;            // 0..511
    int row = idx >> 3, off = (idx & 7) * 8;
    *reinterpret_cast<uint4*>(&t[row][off]) =
        *reinterpret_cast<const uint4*>(V + ((size_t)bh * SEQ + s0 + row) * HDIM + off);
  }
  __syncthreads();
  #pragma unroll
  for (int it = 0; it < 2; ++it){
    int idx = it * 256 + tid;
    int d = idx >> 3, soff = (idx & 7) * 8;
    short8 v;
    #pragma unroll
    for (int e = 0; e < 8; ++e) v[e] = (short)t[soff + e][d];
    *reinterpret_cast<short8*>(Vt + ((size_t)bh * HDIM + d) * SEQ + s0 + soff) = v;
  }
}

// ---------------- output GEMM: out = ao @ Wo^T + bo (fp32 out) ----------------
// Unchanged 16x16 control (R10): 2-phase dbuf; 256 blocks; m pinned per XCD, n fast.
__global__ __launch_bounds__(256) void gemm_out(
    const ushort* __restrict__ A, const ushort* __restrict__ Bw,
    const float* __restrict__ bias, float* __restrict__ Co)
{
  constexpr int BM = 128, BN = 128, BK = 32;
  __shared__ __attribute__((aligned(16))) ushort As[2][BM*BK];
  __shared__ __attribute__((aligned(16))) ushort Bs[2][BN*BK];
  const int tid  = threadIdx.x;
  const int lane = tid & 63;
  const int wid  = tid >> 6;
  const int wr = wid >> 1, wc = wid & 1;

  const int bid = blockIdx.x;
  const int xcd = bid & 7, i = bid >> 3;       // i in 0..31
  const int m0 = (xcd * 4 + (i >> 3)) * BM;
  const int n0 = (i & 7) * BN;

  const int cc0 = tid, cc1 = tid + 256;
  const int row0 = cc0 >> 2, off0 = (cc0 & 3) * 8;
  const int row1 = cc1 >> 2, off1 = (cc1 & 3) * 8;
  const ushort* A0 = A  + (size_t)(m0 + row0) * KDIM + off0;
  const ushort* A1 = A  + (size_t)(m0 + row1) * KDIM + off1;
  const ushort* B0 = Bw + (size_t)(n0 + row0) * KDIM + off0;
  const ushort* B1 = Bw + (size_t)(n0 + row1) * KDIM + off1;

  floatx4 acc[4][4];
  #pragma unroll
  for (int ii = 0; ii < 4; ++ii)
    #pragma unroll
    for (int j = 0; j < 4; ++j) acc[ii][j] = (floatx4){0.f, 0.f, 0.f, 0.f};

  const int rsel = lane & 15, ksel = (lane >> 4) * 8;

  gload16(A0, &As[0][cc0 * 8]);
  gload16(B0, &Bs[0][cc0 * 8]);
  gload16(A1, &As[0][cc1 * 8]);
  gload16(B1, &Bs[0][cc1 * 8]);
  __syncthreads();

  int cur = 0;
  for (int kk = 0; kk < KDIM; kk += BK){
    if (kk + BK < KDIM){
      gload16(A0 + kk + BK, &As[cur ^ 1][cc0 * 8]);
      gload16(B0 + kk + BK, &Bs[cur ^ 1][cc0 * 8]);
      gload16(A1 + kk + BK, &As[cur ^ 1][cc1 * 8]);
      gload16(B1 + kk + BK, &Bs[cur ^ 1][cc1 * 8]);
    }
    short8 af[4], bfr[4];
    #pragma unroll
    for (int m = 0; m < 4; ++m)
      af[m] = *reinterpret_cast<const short8*>(&As[cur][(wr*64 + m*16 + rsel) * BK + ksel]);
    #pragma unroll
    for (int n = 0; n < 4; ++n)
      bfr[n] = *reinterpret_cast<const short8*>(&Bs[cur][(wc*64 + n*16 + rsel) * BK + ksel]);
    #pragma unroll
    for (int m = 0; m < 4; ++m)
      #pragma unroll
      for (int n = 0; n < 4; ++n)
        acc[m][n] = __builtin_amdgcn_mfma_f32_16x16x32_bf16(af[m], bfr[n], acc[m][n], 0, 0, 0);
    __syncthreads();
    cur ^= 1;
  }

  #pragma unroll
  for (int m = 0; m < 4; ++m)
    #pragma unroll
    for (int n = 0; n < 4; ++n)
      #pragma unroll
      for (int r = 0; r < 4; ++r){
        int mg = m0 + wr*64 + m*16 + (lane >> 4)*4 + r;
        int ng = n0 + wc*64 + n*16 + (lane & 15);
        Co[(size_t)mg * EMBED + ng] = acc[m][n][r] + bias[ng];
      }
}

// ---------------- local attention: MFMA scores + softmax + full-row write + MFMA PV ----------------
__global__ __launch_bounds__(256) void attn_kernel(
    const ushort* __restrict__ Qb, const ushort* __restrict__ Kb, const ushort* __restrict__ Vt,
    float* __restrict__ attnp, ushort* __restrict__ ao)
{
  constexpr int TQ = 16;
  constexpr int SPAD = 292;   // f32 stride
  constexpr int PPAD = 296;   // ushort stride
  __shared__ __attribute__((aligned(16))) float  Ss[TQ][SPAD];
  __shared__ __attribute__((aligned(16))) ushort Pb[TQ][PPAD];
  __shared__ float rowinv[TQ];

  const int tid  = threadIdx.x;
  const int lane = tid & 63;
  const int w    = tid >> 6;      // wave 0..3
  const int l15  = lane & 15;
  const int lhi  = lane >> 4;     // 0..3
  const int qt = blockIdx.x;      // 0..127
  const int bh = blockIdx.y;      // 0..31
  const int q0 = qt * TQ;
  const int c0 = max(0, q0 - HALFW);
  const int c1 = min(SEQ, q0 + TQ + HALFW);   // c0,c1 multiples of 16
  const int nc = c1 - c0;                     // 144..272
  const int ntiles = nc >> 4;
  const int nks = (nc + 31) >> 5;             // 32-key slices for PV

  // ---- scores: S = Q @ K^T via mfma 16x16x32, straight from global ----
  const ushort* Qrow = Qb + ((size_t)bh * SEQ + q0 + l15) * HDIM + lhi * 8;
  const short8 aq0 = *reinterpret_cast<const short8*>(Qrow);
  const short8 aq1 = *reinterpret_cast<const short8*>(Qrow + 32);

  for (int t = w; t < ntiles; t += 4){
    const ushort* Krow = Kb + ((size_t)bh * SEQ + c0 + t*16 + l15) * HDIM + lhi * 8;
    short8 bk0 = *reinterpret_cast<const short8*>(Krow);
    short8 bk1 = *reinterpret_cast<const short8*>(Krow + 32);
    floatx4 acc = (floatx4){0.f, 0.f, 0.f, 0.f};
    acc = __builtin_amdgcn_mfma_f32_16x16x32_bf16(aq0, bk0, acc, 0, 0, 0);
    acc = __builtin_amdgcn_mfma_f32_16x16x32_bf16(aq1, bk1, acc, 0, 0, 0);
    const int c = c0 + t*16 + l15;
    #pragma unroll
    for (int r = 0; r < 4; ++r){
      int q = q0 + lhi*4 + r;
      float s = (c < q - HALFW || c > q + HALFW) ? -1e30f : acc[r] * 0.125f;
      Ss[lhi*4 + r][t*16 + l15] = s;
    }
  }
  __syncthreads();

  // ---- softmax over row r (16 threads per row) ----
  const int r  = tid >> 4;
  const int lc = tid & 15;
  float mx = -1e30f;
  for (int j = lc; j < nc; j += 16) mx = fmaxf(mx, Ss[r][j]);
  #pragma unroll
  for (int o = 1; o < 16; o <<= 1) mx = fmaxf(mx, __shfl_xor(mx, o, 64));
  float sum = 0.f;
  for (int j = lc; j < nc; j += 16){
    float p = __expf(Ss[r][j] - mx);
    Ss[r][j] = p;
    Pb[r][j] = f2bf(p);
    sum += p;
  }
  for (int j = nc + lc; j < nks * 32; j += 16) Pb[r][j] = 0;
  #pragma unroll
  for (int o = 1; o < 16; o <<= 1) sum += __shfl_xor(sum, o, 64);
  if (lc == 0) rowinv[r] = 1.f / sum;
  __syncthreads();

  // ---- full attn rows: zeros outside [c0,c1), p*inv inside ----
  const int jz0 = c0 >> 2, jz1 = c1 >> 2;
  const floatx4 zero4 = (floatx4){0.f, 0.f, 0.f, 0.f};
  for (int rr = 0; rr < TQ; ++rr){
    const float inv = rowinv[rr];
    floatx4* dst = reinterpret_cast<floatx4*>(attnp + ((size_t)bh * SEQ + (q0 + rr)) * SEQ);
    #pragma unroll
    for (int it = 0; it < SEQ / 4 / 256; ++it){
      int j4 = it * 256 + tid;
      floatx4 v = zero4;
      if (j4 >= jz0 && j4 < jz1){
        floatx4 p = *reinterpret_cast<const floatx4*>(&Ss[rr][j4 * 4 - c0]);
        v = (floatx4){p[0] * inv, p[1] * inv, p[2] * inv, p[3] * inv};
      }
      __builtin_nontemporal_store(v, &dst[j4]);
    }
  }

  // ---- PV via mfma: V from global (transposed layout) ----
  floatx4 oacc = (floatx4){0.f, 0.f, 0.f, 0.f};
  const ushort* Vrow = Vt + ((size_t)bh * HDIM + w*16 + l15) * SEQ + c0 + lhi * 8;
  for (int ks = 0; ks < nks; ++ks){
    short8 ap = *reinterpret_cast<const short8*>(&Pb[l15][ks*32 + lhi*8]);
    short8 bv = *reinterpret_cast<const short8*>(Vrow + ks*32);
    oacc = __builtin_amdgcn_mfma_f32_16x16x32_bf16(ap, bv, oacc, 0, 0, 0);
  }
  const int b = bh >> 4, h = bh & 15;
  #pragma unroll
  for (int rr = 0; rr < 4; ++rr){
    int q = q0 + lhi*4 + rr;
    float val = oacc[rr] * rowinv[lhi*4 + rr];
    ao[((size_t)(b * SEQ + q)) * EMBED + h * HDIM + w*16 + l15] = f2bf(val);
  }
}

extern "C" void kernel_launch(void* const* d_in, const int* in_sizes, int n_in,
                              void* d_out, int out_size, void* d_ws, size_t ws_size,
                              hipStream_t stream)
{
  const float* x  = (const float*)d_in[0];
  const float* Wq = (const float*)d_in[1];
  const float* bq = (const float*)d_in[2];
  const float* Wk = (const float*)d_in[3];
  const float* bk = (const float*)d_in[4];
  const float* Wv = (const float*)d_in[5];
  const float* bv = (const float*)d_in[6];
  const float* Wo = (const float*)d_in[7];
  const float* bo = (const float*)d_in[8];

  char* ws = (char*)d_ws;
  ushort* xb   = (ushort*)(ws);                 // x bf16 [4096][1024]   (reused as Vt later)
  ushort* wqkv = (ushort*)(ws + 8388608);       // Wq|Wk|Wv bf16
  ushort* wo   = (ushort*)(ws + 14680064);      // Wo bf16
  ushort* Qb   = (ushort*)(ws + 16777216);      // Q bf16 [b,h,s,d]
  ushort* Kb   = (ushort*)(ws + 25165824);      // K bf16 [b,h,s,d]
  ushort* Vb   = (ushort*)(ws + 33554432);      // V bf16 [b,h,s,d]
  ushort* ao   = (ushort*)(ws + 41943040);      // attn out bf16 [b,s,e]
  ushort* Vt   = (ushort*)(ws);                 // V^T bf16 [b,h,d,s] — aliases xb (dead after gemm_qkv)

  float* outp  = (float*)d_out;                           // [2,2048,1024]
  float* attnp = outp + (size_t)MTOT * EMBED;             // [2,16,2048,2048]

  cast_all<<<8192, 256, 0, stream>>>(x, xb, Wq, Wk, Wv, wqkv, Wo, wo);
  gemm_qkv<<<768, 256, 0, stream>>>(xb, wqkv, bq, bk, bv, Qb, Kb, Vb);
  transposeV<<<dim3(32, 32), 256, 0, stream>>>(Vb, Vt);
  attn_kernel<<<dim3(128, 32), 256, 0, stream>>>(Qb, Kb, Vt, attnp, ao);
  gemm_out<<<256, 256, 0, stream>>>(ao, wo, bo, outp);
}